// Round 11
// baseline (461.035 us; speedup 1.0000x reference)
//
#include <hip/hip_runtime.h>
#include <hip/hip_bf16.h>
#include <math.h>

// ---------------------------------------------------------------------------
// GCN pipeline v4: dst-sorted CSR + wave-per-node register aggregation,
// layer-2 intermediate (y2) stored as bf16x16 = 32B records to double the
// per-XCD L2 hit rate of the random neighbor gather (12.8MB -> 6.4MB table).
//   1) bin edges by dst bucket (BN=512), LDS-staged coalesced flush
//   2) per-bucket counting sort by local dst -> CSR; fused deg/dinv/y1 prep
//   3) k_l1: wave-per-node, 3-dim gather + shfl reduce + 3x16 GEMM + ReLU,
//      epilogue packs y2 to bf16 (RNE)
//   4) k_l2: wave-per-node, 2 lanes/edge x 16B (8 bf16 feats each),
//      32 edges/iter, shfl reduce, 16x32 GEMM + ReLU + mean-pool atomics
// ---------------------------------------------------------------------------

#define TPB 256
#define BSH 9
#define BN 512             // destination nodes per bucket
#define NBMAX 512
#define EPT 16             // edges per thread in k_bin
#define CAPL 16            // staging slots per bucket per chunk
#define ROWM 0x3FFFF

__device__ __forceinline__ void atomAddF(float* p, float v) {
    unsafeAtomicAdd(p, v);   // hardware global_atomic_add_f32
}

// bf16 helpers (RNE pack, cheap unpack)
__device__ __forceinline__ unsigned f2bf(float x) {
    unsigned u = __float_as_uint(x);
    return (u + 0x7FFFu + ((u >> 16) & 1u)) >> 16;
}
__device__ __forceinline__ float bflo(unsigned w) { return __uint_as_float(w << 16); }
__device__ __forceinline__ float bfhi(unsigned w) { return __uint_as_float(w & 0xFFFF0000u); }

// --- K0: cursor init: cur[b] = b*CAPB ---
__global__ void k_curinit(int* __restrict__ cur, int NB, int CAPB) {
    int t = threadIdx.x;
    for (int b = t; b < NB; b += TPB) cur[b] = b * CAPB;
}

// --- K1: LDS-staged binning. Each block owns one 4096-edge chunk. ---
__global__ void k_bin(const int* __restrict__ row, const int* __restrict__ col, int E,
                      int NB, int* __restrict__ cur, unsigned* __restrict__ blist) {
    __shared__ unsigned lh[NBMAX * CAPL];
    __shared__ int lcnt[NBMAX];
    __shared__ int gb[NBMAX];
    const int t = threadIdx.x;
    for (int j = t; j < NBMAX; j += TPB) lcnt[j] = 0;
    __syncthreads();
    const int base = blockIdx.x * (TPB * EPT);
#pragma unroll 4
    for (int j = 0; j < EPT; ++j) {
        int e = base + j * TPB + t;
        if (e < E) {
            int c = col[e];
            int b = c >> BSH;
            unsigned val = (unsigned)row[e] | ((unsigned)(c & (BN - 1)) << 18);
            int pos = atomicAdd(&lcnt[b], 1);
            if (pos < CAPL) lh[b * CAPL + pos] = val;
            else { int gp = atomicAdd(&cur[b], 1); blist[gp] = val; }  // rare spill
        }
    }
    __syncthreads();
    for (int b = t; b < NB; b += TPB) {
        int c = min(lcnt[b], CAPL);
        gb[b] = c ? atomicAdd(&cur[b], c) : 0;
    }
    __syncthreads();
    for (int slot = t; slot < NB * CAPL; slot += TPB) {
        int b = slot >> 4;               // CAPL = 16
        int p = slot & (CAPL - 1);
        if (p < min(lcnt[b], CAPL)) blist[gb[b] + p] = lh[slot];
    }
}

// --- K2: per-bucket counting sort by local dst -> CSR; fused deg/dinv/y1 prep.
//     nod[i] = (csr_offset) | (deg << 23);  bl2[] = source row indices. ---
__global__ void k_lcsort(const unsigned* __restrict__ bl, const int* __restrict__ bend,
                         int CAPB, const float* __restrict__ x,
                         unsigned* __restrict__ bl2, unsigned* __restrict__ nod,
                         float* __restrict__ dinv, float4* __restrict__ y1, int N) {
    __shared__ int hist[BN];
    __shared__ int pre[BN];
    __shared__ int scur[BN];
    __shared__ int s[TPB];
    const int t = threadIdx.x, b = blockIdx.x;
    for (int j = t; j < BN; j += TPB) hist[j] = 0;
    __syncthreads();
    const int lo = b * CAPB, hi = bend[b];
    for (int k = lo + t; k < hi; k += TPB)
        atomicAdd(&hist[bl[k] >> 18], 1);
    __syncthreads();
    // exclusive scan of 512 bins via 256 pair-partials (Hillis-Steele)
    const int t2 = t * 2;
    s[t] = hist[t2] + hist[t2 + 1];
    __syncthreads();
    for (int d = 1; d < TPB; d <<= 1) {
        int v = (t >= d) ? s[t - d] : 0;
        __syncthreads();
        s[t] += v;
        __syncthreads();
    }
    int base0 = (t == 0) ? 0 : s[t - 1];
    pre[t2] = base0;
    pre[t2 + 1] = base0 + hist[t2];
    scur[t2] = pre[t2];
    scur[t2 + 1] = pre[t2 + 1];
    // fused node prep (2 nodes per thread)
#pragma unroll
    for (int j = 0; j < 2; ++j) {
        int lcl = t2 + j;
        int i = b * BN + lcl;
        if (i < N) {
            int deg = hist[lcl];
            nod[i] = (unsigned)(lo + pre[lcl]) | ((unsigned)deg << 23);
            float d = rsqrtf(1.0f + (float)deg);
            dinv[i] = d;
            float4 v;
            v.x = x[3 * (size_t)i + 0] * d;
            v.y = x[3 * (size_t)i + 1] * d;
            v.z = x[3 * (size_t)i + 2] * d;
            v.w = 0.0f;
            y1[i] = v;
        }
    }
    __syncthreads();
    // scatter: dst-sorted within bucket => globally dst-sorted CSR
    for (int k = lo + t; k < hi; k += TPB) {
        unsigned pv = bl[k];
        int lc = pv >> 18;
        int pos = atomicAdd(&scur[lc], 1);
        bl2[lo + pos] = pv & ROWM;
    }
}

// --- K3: layer1, one wave per node: 64-lane gather + shfl reduce + 3x16 GEMM,
//     epilogue packs h1*dinv to bf16x16 (32B record) ---
__global__ void k_l1(const unsigned* __restrict__ bl2, const unsigned* __restrict__ nod,
                     const float4* __restrict__ y1, const float* __restrict__ dinv,
                     const float* __restrict__ W1, const float* __restrict__ b1,
                     unsigned* __restrict__ y2b, int N) {
    __shared__ float sW[48];
    __shared__ float sb[16];
    if (threadIdx.x < 48) sW[threadIdx.x] = W1[threadIdx.x];
    if (threadIdx.x < 16) sb[threadIdx.x] = b1[threadIdx.x];
    __syncthreads();
    const int lane = threadIdx.x & 63;
    const int i = blockIdx.x * 4 + (threadIdx.x >> 6);
    if (i >= N) return;
    const unsigned u = nod[i];
    const int s = u & 0x7FFFFF;
    const int e = s + (int)(u >> 23);
    float ax = 0.f, ay = 0.f, az = 0.f;
    for (int k = s + lane; k < e; k += 64) {
        float4 v = y1[bl2[k]];
        ax += v.x; ay += v.y; az += v.z;
    }
#pragma unroll
    for (int m = 1; m < 64; m <<= 1) {
        ax += __shfl_xor(ax, m);
        ay += __shfl_xor(ay, m);
        az += __shfl_xor(az, m);
    }
    float4 a = y1[i];                  // self-loop (pre-scaled)
    const float d = dinv[i];
    ax = (ax + a.x) * d; ay = (ay + a.y) * d; az = (az + a.z) * d;
    float tv = 0.f;
    if (lane < 16) {
        tv = sb[lane] + ax * sW[lane] + ay * sW[16 + lane] + az * sW[32 + lane];
        tv = fmaxf(tv, 0.0f) * d;      // relu + prescale for layer 2
    }
    float tvo = __shfl_xor(tv, 1);     // partner feature (f^1)
    if (lane < 16 && !(lane & 1)) {
        unsigned w = f2bf(tv) | (f2bf(tvo) << 16);   // (f, f+1) packed
        y2b[(size_t)i * 8 + (lane >> 1)] = w;
    }
}

// --- K4: layer2, one wave per node: 2 lanes/edge x 16B (8 bf16 feats),
//     32 edges/iter, shfl reduce + broadcast, 16x32 GEMM + relu + pool ---
__global__ void k_l2(const unsigned* __restrict__ bl2, const unsigned* __restrict__ nod,
                     const unsigned* __restrict__ y2b, const float* __restrict__ dinv,
                     const float* __restrict__ W2, const float* __restrict__ b2,
                     const int* __restrict__ batch,
                     float* __restrict__ gsum, float* __restrict__ gcnt, int N) {
    __shared__ float sW[512];
    __shared__ float sb[32];
    for (int j = threadIdx.x; j < 512; j += TPB) sW[j] = W2[j];
    if (threadIdx.x < 32) sb[threadIdx.x] = b2[threadIdx.x];
    __syncthreads();
    const int lane = threadIdx.x & 63;
    const int q = lane & 1, eo = lane >> 1;          // 2 lanes per edge
    const int i = blockIdx.x * 4 + (threadIdx.x >> 6);
    if (i >= N) return;
    const unsigned u = nod[i];
    const int s = u & 0x7FFFFF;
    const int e = s + (int)(u >> 23);
    const uint4* y2q = (const uint4*)y2b;            // 16B half-records
    float a0=0.f,a1=0.f,a2=0.f,a3=0.f,a4=0.f,a5=0.f,a6=0.f,a7=0.f;
    for (int k = s + eo; k < e; k += 32) {
        int r = bl2[k];                              // 2 lanes broadcast-read
        uint4 w = y2q[(size_t)r * 2 + q];
        a0 += bflo(w.x); a1 += bfhi(w.x);
        a2 += bflo(w.y); a3 += bfhi(w.y);
        a4 += bflo(w.z); a5 += bfhi(w.z);
        a6 += bflo(w.w); a7 += bfhi(w.w);
    }
#pragma unroll
    for (int m = 2; m < 64; m <<= 1) {
        a0 += __shfl_xor(a0, m); a1 += __shfl_xor(a1, m);
        a2 += __shfl_xor(a2, m); a3 += __shfl_xor(a3, m);
        a4 += __shfl_xor(a4, m); a5 += __shfl_xor(a5, m);
        a6 += __shfl_xor(a6, m); a7 += __shfl_xor(a7, m);
    }
    {   // self term (bf16 as well) + dinv scale
        uint4 w = y2q[(size_t)i * 2 + q];
        const float d = dinv[i];
        a0 = (a0 + bflo(w.x)) * d; a1 = (a1 + bfhi(w.x)) * d;
        a2 = (a2 + bflo(w.y)) * d; a3 = (a3 + bfhi(w.y)) * d;
        a4 = (a4 + bflo(w.z)) * d; a5 = (a5 + bfhi(w.z)) * d;
        a6 = (a6 + bflo(w.w)) * d; a7 = (a7 + bfhi(w.w)) * d;
    }
    float v[16];                                     // feats 0-7 from lane0, 8-15 from lane1
    v[0]=__shfl(a0,0);  v[1]=__shfl(a1,0);  v[2]=__shfl(a2,0);  v[3]=__shfl(a3,0);
    v[4]=__shfl(a4,0);  v[5]=__shfl(a5,0);  v[6]=__shfl(a6,0);  v[7]=__shfl(a7,0);
    v[8]=__shfl(a0,1);  v[9]=__shfl(a1,1);  v[10]=__shfl(a2,1); v[11]=__shfl(a3,1);
    v[12]=__shfl(a4,1); v[13]=__shfl(a5,1); v[14]=__shfl(a6,1); v[15]=__shfl(a7,1);
    const int g = batch[i];
    if (lane < 32) {
        float tv = sb[lane];
#pragma unroll
        for (int c = 0; c < 16; ++c) tv += v[c] * sW[c * 32 + lane];
        atomAddF(&gsum[(size_t)g * 32 + lane], fmaxf(tv, 0.0f));
    }
    if (lane == 32) atomAddF(&gcnt[g], 1.0f);
}

// --- K5: mean -> FC -> log_softmax ---
__global__ void k_head(const float* __restrict__ gsum, const float* __restrict__ gcnt,
                       const float* __restrict__ Wfc, const float* __restrict__ bfc,
                       float* __restrict__ out, int G) {
    int g = blockIdx.x * TPB + threadIdx.x;
    if (g < G) {
        float inv = 1.0f / fmaxf(gcnt[g], 1.0f);
        float l0 = bfc[0], l1 = bfc[1];
        const float* gs = gsum + (size_t)g * 32;
#pragma unroll
        for (int j = 0; j < 32; ++j) {
            float m = gs[j] * inv;
            l0 += m * Wfc[j * 2 + 0];
            l1 += m * Wfc[j * 2 + 1];
        }
        float mx = fmaxf(l0, l1);
        float lse = mx + logf(expf(l0 - mx) + expf(l1 - mx));
        out[g * 2 + 0] = l0 - lse;
        out[g * 2 + 1] = l1 - lse;
    }
}

extern "C" void kernel_launch(void* const* d_in, const int* in_sizes, int n_in,
                              void* d_out, int out_size, void* d_ws, size_t ws_size,
                              hipStream_t stream) {
    const float* x     = (const float*)d_in[0];
    const int*   edge  = (const int*)  d_in[1];
    const int*   batch = (const int*)  d_in[2];
    const float* W1    = (const float*)d_in[3];
    const float* b1    = (const float*)d_in[4];
    const float* W2    = (const float*)d_in[5];
    const float* b2    = (const float*)d_in[6];
    const float* Wfc   = (const float*)d_in[7];
    const float* bfc   = (const float*)d_in[8];

    const int N = in_sizes[0] / 3;
    const int E = in_sizes[1] / 2;
    const int G = out_size / 2;
    const int NB = (N + BN - 1) >> BSH;              // 391 for N=200000
    const int CAPB = (E + NB - 1) / NB + 2048;       // mean + ~16 sigma slack
    const int* row = edge;
    const int* col = edge + E;

    // workspace partition (256B aligned)
    char* base = (char*)d_ws;
    size_t o = 0;
    auto take = [&](size_t bytes) { char* r = base + o; o += (bytes + 255) & ~(size_t)255; return r; };
    int*      cur    = (int*)     take((size_t)NB * 4);
    unsigned* blistA = (unsigned*)take((size_t)NB * CAPB * 4);
    unsigned* blistB = (unsigned*)take((size_t)NB * CAPB * 4);
    unsigned* nod    = (unsigned*)take((size_t)N * 4);
    float*    dinv   = (float*)   take((size_t)N * 4);
    float4*   y1     = (float4*)  take((size_t)N * 16);
    unsigned* y2b    = (unsigned*)take((size_t)N * 32);   // bf16x16 records
    float*    gsum   = (float*)   take((size_t)G * 33 * 4);
    float*    gcnt   = gsum + (size_t)G * 32;

    hipMemsetAsync(gsum, 0, (size_t)G * 33 * 4, stream);

    const int gBin = (E + TPB * EPT - 1) / (TPB * EPT);
    const int gW   = (N + 3) / 4;                    // wave-per-node kernels
    const int gG   = (G + TPB - 1) / TPB;

    k_curinit <<<1, TPB, 0, stream>>>(cur, NB, CAPB);
    k_bin     <<<gBin, TPB, 0, stream>>>(row, col, E, NB, cur, blistA);
    k_lcsort  <<<NB, TPB, 0, stream>>>(blistA, cur, CAPB, x, blistB, nod, dinv, y1, N);
    k_l1      <<<gW, TPB, 0, stream>>>(blistB, nod, y1, dinv, W1, b1, y2b, N);
    k_l2      <<<gW, TPB, 0, stream>>>(blistB, nod, y2b, dinv, W2, b2, batch, gsum, gcnt, N);
    k_head    <<<gG, TPB, 0, stream>>>(gsum, gcnt, Wfc, bfc, (float*)d_out, G);
}